// Round 7
// baseline (3545.804 us; speedup 1.0000x reference)
//
#include <hip/hip_runtime.h>

// ---------------------------------------------------------------------------
// ManualLSTM: B=32, S=512, H=1024.
//   Phase A: xg = bf16(x) @ bf16(Wi)  -> bf16 [16384][4096]  (bias in phase B)
//   Phase B: persistent recurrence, 4 INDEPENDENT groups x 64 blocks.
//     R7: flag-free "tagged word" sync. h element stored as u32
//     (step_tag<<16)|bf16 via relaxed AGENT atomics; consumers poll the data
//     words themselves until tag==t. Removes flag store+detect LLC round trip,
//     producer vmcnt(0) drain, and 2 of 4 per-step barriers (R6 chain was
//     3 LLC round trips/step). Wh fragments live in REGISTERS (invariant
//     across steps) — eliminates all B-side ds_reads (R6's 1.4e8 bank
//     conflicts) and the 128KB W LDS image.
//     Deadlock-free: block overwrites buf p with tag t+2 only after gathering
//     all tag t+1, which requires every block's tag-t gather complete.
// ---------------------------------------------------------------------------

typedef __attribute__((ext_vector_type(4))) float f32x4_t;
typedef __attribute__((ext_vector_type(8))) short bf16x8_t;
typedef unsigned long long ull_t;

#define HID   1024
#define SLEN  512
#define NGATE 4096

// ws layout (bytes)
#define XG_OFF    0ULL                      // 16384*4096*2 = 134217728
#define XB_OFF    134217728ULL              // 16384*1024*2 = 33554432
#define WIT_OFF   167772160ULL              // 4096*1024*2  = 8388608
#define WHT_OFF   176160768ULL              // 4096*1024*2  = 8388608
#define TIMG_OFF  184549376ULL              // 4 groups * 2 bufs * 8192 u32 = 262144

#define NBLK_B    256                       // 4 groups x 64 blocks

// persistent-kernel LDS layout
#define H_OFF_L   0                         // 8 rows * 2064B = 16512
#define G_OFF_L   16512                     // gates [16][65] f32 = 4160
#define LDS_TOTAL 20672

__device__ __forceinline__ unsigned short f2bf(float f) {
  unsigned u = __float_as_uint(f);
  u += 0x7fffu + ((u >> 16) & 1u);          // round-nearest-even
  return (unsigned short)(u >> 16);
}
__device__ __forceinline__ float bf2f(unsigned short u) {
  return __uint_as_float(((unsigned)u) << 16);
}
__device__ __forceinline__ float fast_rcp(float x) { return __builtin_amdgcn_rcpf(x); }
__device__ __forceinline__ float sigmoid_f(float x) { return fast_rcp(1.f + __expf(-x)); }
__device__ __forceinline__ float tanh_f(float x) { return 1.f - 2.f * fast_rcp(1.f + __expf(2.f * x)); }

// ---------------------------------------------------------------- converters
__global__ __launch_bounds__(256) void conv_x_bf16(const float* __restrict__ in,
                                                   unsigned short* __restrict__ out) {
  size_t i = (size_t)blockIdx.x * 256 + threadIdx.x;
  const float4* p = (const float4*)in;
  float4 v = p[i];
  ushort4 o;
  o.x = f2bf(v.x); o.y = f2bf(v.y); o.z = f2bf(v.z); o.w = f2bf(v.w);
  ((ushort4*)out)[i] = o;
}

// in: fp32 [1024][4096]  -> out: bf16 [4096][1024]  (out[n][k] = in[k][n])
__global__ void transpose_w_bf16(const float* __restrict__ in,
                                 unsigned short* __restrict__ out) {
  __shared__ float tile[32][33];
  int tx = threadIdx.x, ty = threadIdx.y;        // block (32, 8)
  int n0 = blockIdx.x * 32, k0 = blockIdx.y * 32;
  #pragma unroll
  for (int i = 0; i < 4; i++)
    tile[ty + 8 * i][tx] = in[(size_t)(k0 + ty + 8 * i) * NGATE + n0 + tx];
  __syncthreads();
  #pragma unroll
  for (int i = 0; i < 4; i++)
    out[(size_t)(n0 + ty + 8 * i) * HID + k0 + tx] = f2bf(tile[tx][ty + 8 * i]);
}

// zero all 4 groups' double-buffered tagged images (tag0 | h=0 == 0u)
__global__ void init_ws(unsigned* __restrict__ timg) {
  size_t i = (size_t)blockIdx.x * 256 + threadIdx.x;   // 16384 threads
  #pragma unroll
  for (int k = 0; k < 4; k++) timg[i + k * 16384] = 0u;  // 65536 u32 total
}

// ---------------------------------------------------------------- Phase A
// C[16384][4096] bf16 = A[16384][1024] bf16  x  BT[4096][1024] bf16
__global__ __launch_bounds__(256) void gemm_xg(const unsigned short* __restrict__ A,
                                               const unsigned short* __restrict__ BT,
                                               unsigned short* __restrict__ C) {
  extern __shared__ char smem[];
  char* As = smem;                 // 128 rows * 80B (32 bf16 + 16B pad)
  char* Bs = smem + 10240;
  const int tid = threadIdx.x;
  const int lane = tid & 63, w = tid >> 6, q = lane >> 4, l16 = lane & 15;
  const int wm = w & 1, wn = w >> 1;
  const size_t m0 = (size_t)blockIdx.y * 128, n0 = (size_t)blockIdx.x * 128;

  f32x4_t acc[4][4];
  #pragma unroll
  for (int i = 0; i < 4; i++)
    #pragma unroll
    for (int j = 0; j < 4; j++) acc[i][j] = (f32x4_t){0.f, 0.f, 0.f, 0.f};

  for (int kk = 0; kk < 32; kk++) {
    const int k0 = kk * 32;
    #pragma unroll
    for (int h = 0; h < 2; h++) {
      int idx = tid + h * 256;              // 0..511
      int r = idx >> 2, ch = idx & 3;
      uint4 va = *(const uint4*)((const char*)A + ((m0 + r) * HID + k0) * 2 + ch * 16);
      *(uint4*)(As + r * 80 + ch * 16) = va;
      uint4 vb = *(const uint4*)((const char*)BT + ((n0 + r) * HID + k0) * 2 + ch * 16);
      *(uint4*)(Bs + r * 80 + ch * 16) = vb;
    }
    __syncthreads();
    bf16x8_t af[4], bf[4];
    #pragma unroll
    for (int mt = 0; mt < 4; mt++)
      af[mt] = *(const bf16x8_t*)(As + (wm * 64 + mt * 16 + l16) * 80 + q * 16);
    #pragma unroll
    for (int nt = 0; nt < 4; nt++)
      bf[nt] = *(const bf16x8_t*)(Bs + (wn * 64 + nt * 16 + l16) * 80 + q * 16);
    #pragma unroll
    for (int mt = 0; mt < 4; mt++)
      #pragma unroll
      for (int nt = 0; nt < 4; nt++)
        acc[mt][nt] = __builtin_amdgcn_mfma_f32_16x16x32_bf16(af[mt], bf[nt], acc[mt][nt], 0, 0, 0);
    __syncthreads();
  }

  // epilogue: stage C tile (bf16 [128][136]) through LDS for coalesced stores
  unsigned short* cst = (unsigned short*)smem;
  #pragma unroll
  for (int mt = 0; mt < 4; mt++)
    #pragma unroll
    for (int nt = 0; nt < 4; nt++)
      #pragma unroll
      for (int r = 0; r < 4; r++) {
        int m = wm * 64 + mt * 16 + q * 4 + r;
        int n = wn * 64 + nt * 16 + l16;
        cst[m * 136 + n] = f2bf(acc[mt][nt][r]);
      }
  __syncthreads();
  #pragma unroll
  for (int i = 0; i < 8; i++) {
    int idx = tid + i * 256;                // < 2048
    int row = idx >> 4, ch = idx & 15;
    uint4 v = *(const uint4*)((const char*)cst + row * 272 + ch * 16);
    *(uint4*)((char*)C + ((m0 + row) * NGATE + n0) * 2 + ch * 16) = v;
  }
}

// ---------------------------------------------------------------- Phase B
// 4 groups x 64 blocks x 256 threads. Group = 8 batches, full gate dim.
// Block m: hidden cols m*16..+16 => local gate cols n = G*16+j, G=0..3.
// Tagged image per group: u32 [2 bufs][8 batches][1024 cols].
__global__ __launch_bounds__(256, 1) void lstm_persistent(
    const unsigned short* __restrict__ xg,   // [16384][4096] bf16
    const unsigned short* __restrict__ whT,  // [4096][1024] bf16
    const float* __restrict__ bias,          // [4096]
    float* __restrict__ out,                 // [32][512][1024]
    unsigned* timg) {                        // 4 * 2 * 8192 u32
  extern __shared__ char smem[];
  char* h_lds = smem + H_OFF_L;                    // [8 rows b][2048B k] +16B pad
  float* gates = (float*)(smem + G_OFF_L);         // [16][65] f32 (rows 8-15 dup)

  const int tid = threadIdx.x;
  const int lane = tid & 63, wv = tid >> 6, q = lane >> 4, l16 = lane & 15;
  const int g = blockIdx.x >> 6;                   // group 0..3
  const int m = blockIdx.x & 63;                   // member 0..63
  const int b_l = tid >> 4, j_l = tid & 15;        // EW mapping (tid<128)

  // Wh fragments pinned in REGISTERS (invariant across steps):
  // lane's local gate col n = wv*16 + l16 -> whT row wv*1024 + m*16 + l16,
  // fragment kk at byte offset q*16 + kk*64 (B[k=kk*32+q*8+j][n]).
  bf16x8_t wfrag[32];
  {
    const char* wrow = (const char*)whT +
        ((size_t)wv * 1024 + m * 16 + l16) * 2048 + q * 16;
    #pragma unroll
    for (int kk = 0; kk < 32; kk++)
      wfrag[kk] = *(const bf16x8_t*)(wrow + kk * 64);
  }
  float bsr[4];
  #pragma unroll
  for (int G = 0; G < 4; G++) bsr[G] = bias[G * 1024 + m * 16 + j_l];
  float c_st = 0.f;
  const char* arow = h_lds + (l16 & 7) * 2064 + q * 16;   // A: m=l16 (&7 mirror)
  unsigned* tg = timg + g * 16384;                 // 2 bufs * 8192 u32

  for (int t = 0; t < SLEN; t++) {
    // xg prefetch (no h dependency) — overlaps the tag-poll
    unsigned short xgv[4];
    if (tid < 128) {
      const unsigned short* p =
          xg + ((size_t)(g * 8 + b_l) * 512 + t) * 4096 + m * 16 + j_l;
      xgv[0] = p[0]; xgv[1] = p[1024]; xgv[2] = p[2048]; xgv[3] = p[3072];
    }

    // gather tagged image buf (t&1): 4096 ulls (= 2 tagged words each);
    // issue all 16 loads (pipelined), then check tags in arrival order,
    // re-polling stragglers individually. Tag must equal t exactly.
    ull_t* src = (ull_t*)(tg + (t & 1) * 8192);
    ull_t v[16];
    #pragma unroll
    for (int k = 0; k < 16; k++)
      v[k] = __hip_atomic_load(src + tid + k * 256, __ATOMIC_RELAXED,
                               __HIP_MEMORY_SCOPE_AGENT);
    const unsigned tt = (unsigned)t;
    #pragma unroll
    for (int k = 0; k < 16; k++) {
      while ((((unsigned)(v[k] >> 16) & 0xFFFFu) != tt) |
             ((unsigned)(v[k] >> 48) != tt))
        v[k] = __hip_atomic_load(src + tid + k * 256, __ATOMIC_RELAXED,
                                 __HIP_MEMORY_SCOPE_AGENT);
      int idx = tid + k * 256;
      int row = idx >> 9, cpair = idx & 511;       // 512 ulls per 1024-col row
      unsigned packed = ((unsigned)v[k] & 0xFFFFu) |
                        ((unsigned)(v[k] >> 16) & 0xFFFF0000u);
      *(unsigned*)(h_lds + row * 2064 + cpair * 4) = packed;
    }
    __syncthreads();   // h_lds complete; also fences prior-step gates reads

    // gates[b][n] = sum_k h[b][k] * Wh[k][n]; A from LDS, B from registers
    f32x4_t acc0 = (f32x4_t){0.f, 0.f, 0.f, 0.f};
    f32x4_t acc1 = (f32x4_t){0.f, 0.f, 0.f, 0.f};
    #pragma unroll
    for (int kk = 0; kk < 32; kk += 2) {
      bf16x8_t a0 = *(const bf16x8_t*)(arow + kk * 64);
      acc0 = __builtin_amdgcn_mfma_f32_16x16x32_bf16(a0, wfrag[kk], acc0, 0, 0, 0);
      bf16x8_t a1 = *(const bf16x8_t*)(arow + kk * 64 + 64);
      acc1 = __builtin_amdgcn_mfma_f32_16x16x32_bf16(a1, wfrag[kk + 1], acc1, 0, 0, 0);
    }
    #pragma unroll
    for (int r = 0; r < 4; r++) {
      int bb = q * 4 + r;                          // rows 8-15 are duplicates
      gates[bb * 65 + wv * 16 + l16] = acc0[r] + acc1[r];
    }
    __syncthreads();   // gates ready; also fences h_lds MFMA reads vs next gather

    // elementwise: 128 threads own (b_l, j_l); store tagged word (fire and
    // forget — the tag IS the flag; no drain, no barrier, no flag store)
    if (tid < 128) {
      float gi = gates[b_l * 65 + j_l]      + bsr[0] + bf2f(xgv[0]);
      float gf = gates[b_l * 65 + 16 + j_l] + bsr[1] + bf2f(xgv[1]);
      float gg = gates[b_l * 65 + 32 + j_l] + bsr[2] + bf2f(xgv[2]);
      float go = gates[b_l * 65 + 48 + j_l] + bsr[3] + bf2f(xgv[3]);
      float i_s = sigmoid_f(gi), f_s = sigmoid_f(gf);
      float g_t = tanh_f(gg), o_s = sigmoid_f(go);
      c_st = f_s * c_st + i_s * g_t;
      float h = o_s * tanh_f(c_st);
      unsigned wword = ((unsigned)(t + 1) << 16) | (unsigned)f2bf(h);
      __hip_atomic_store(tg + ((t + 1) & 1) * 8192 + b_l * 1024 + m * 16 + j_l,
                         wword, __ATOMIC_RELAXED, __HIP_MEMORY_SCOPE_AGENT);
      out[((size_t)(g * 8 + b_l) * 512 + t) * 1024 + m * 16 + j_l] = h;
    }
  }
}

// ---------------------------------------------------------------- launcher
extern "C" void kernel_launch(void* const* d_in, const int* in_sizes, int n_in,
                              void* d_out, int out_size, void* d_ws, size_t ws_size,
                              hipStream_t stream) {
  const float* x    = (const float*)d_in[0];   // [32,512,1024]
  const float* wi   = (const float*)d_in[1];   // [1024,4096]
  const float* wh   = (const float*)d_in[2];   // [1024,4096]
  const float* bias = (const float*)d_in[3];   // [4096]
  float* out = (float*)d_out;

  char* ws = (char*)d_ws;
  unsigned short* xg   = (unsigned short*)(ws + XG_OFF);
  unsigned short* xb   = (unsigned short*)(ws + XB_OFF);
  unsigned short* wiT  = (unsigned short*)(ws + WIT_OFF);
  unsigned short* whT  = (unsigned short*)(ws + WHT_OFF);
  unsigned* timg       = (unsigned*)(ws + TIMG_OFF);

  conv_x_bf16<<<16384, 256, 0, stream>>>(x, xb);
  transpose_w_bf16<<<dim3(128, 32), dim3(32, 8), 0, stream>>>(wi, wiT);
  transpose_w_bf16<<<dim3(128, 32), dim3(32, 8), 0, stream>>>(wh, whT);
  init_ws<<<64, 256, 0, stream>>>(timg);
  gemm_xg<<<dim3(32, 128), 256, 34816, stream>>>(xb, wiT, xg);
  lstm_persistent<<<NBLK_B, 256, LDS_TOTAL, stream>>>(xg, whT, bias, out, timg);
}